// Round 8
// baseline (72.769 us; speedup 1.0000x reference)
//
#include <hip/hip_runtime.h>
#include <math.h>

// out (32,64,16,2048) f32 = one_hot(ascending-sorted top-16 indices of logits+gn).
// Forward value of stop_gradient(hard-soft)+soft == hard exactly (0) / ~1ulp (1).
//
// Two kernels:
//   A: per-wave top-16 selection -> onecol[32768] (flat index == global output row)
//   B: GRID-STRIDED dense-front writer: all resident waves sweep one ~8MB stripe
//      together (fill-kernel-style DRAM row locality), 32 preloaded indices per
//      block, pure streaming float4 stores with the 1.0 injected inline.
#define K_SEL   16
#define VOCAB   2048
#define NROWS   2048    // BS(32) * D0(64)

__global__ __launch_bounds__(64) void topk_select_kernel(
    const float* __restrict__ logits,   // (64, 2048)
    const float* __restrict__ gn,       // (32, 64, 2048)
    int* __restrict__ onecol)           // (32768): one-hot col for global out row
{
    const int row  = blockIdx.x;        // row = bs*64 + d0
    const int d0   = row & 63;
    const int lane = threadIdx.x;       // 0..63 (one wave)

    const float* grow = gn     + (size_t)row * VOCAB;
    const float* lrow = logits + (size_t)d0  * VOCAB;

    // lane owns columns c = seg*256 + lane*4 + j, seg=0..7, j=0..3
    float v[32];
    #pragma unroll
    for (int seg = 0; seg < 8; ++seg) {
        const int c = seg * 256 + lane * 4;
        const float4 g = *reinterpret_cast<const float4*>(grow + c);
        const float4 l = *reinterpret_cast<const float4*>(lrow + c);
        v[seg * 4 + 0] = l.x + g.x;
        v[seg * 4 + 1] = l.y + g.y;
        v[seg * 4 + 2] = l.z + g.z;
        v[seg * 4 + 3] = l.w + g.w;
    }

    // local argmax; ascending scan + strict '>' keeps lowest index on ties
    float lv = v[0]; int ls = 0;
    #pragma unroll
    for (int i = 1; i < 32; ++i) { if (v[i] > lv) { lv = v[i]; ls = i; } }

    int sel[K_SEL];

    // 16 rounds of wave argmax on (value desc, col asc) = lax.top_k order
    #pragma unroll
    for (int k = 0; k < K_SEL; ++k) {
        float bv = lv;
        int   bc = ((ls >> 2) << 8) + lane * 4 + (ls & 3);
        #pragma unroll
        for (int off = 1; off < 64; off <<= 1) {
            const float ov = __shfl_xor(bv, off);
            const int   oc = __shfl_xor(bc, off);
            if (ov > bv || (ov == bv && oc < bc)) { bv = ov; bc = oc; }
        }
        sel[k] = bc;  // wave-uniform after butterfly
        // owner lane knocks out the winner and rescans its local max
        if (lane == ((bc >> 2) & 63)) {
            const int s = (((bc >> 8) & 7) << 2) | (bc & 3);
            lv = -INFINITY; ls = 0;
            #pragma unroll
            for (int i = 0; i < 32; ++i) {
                if (i == s) v[i] = -INFINITY;
                if (v[i] > lv) { lv = v[i]; ls = i; }
            }
        }
    }

    // lanes 0..15: my = sel[lane] (static cndmask chain), rank by ascending
    // index among the 16 distinct cols -> permutation; one 64B-line store.
    if (lane < K_SEL) {
        int my = sel[0];
        #pragma unroll
        for (int k = 1; k < K_SEL; ++k) { if (lane == k) my = sel[k]; }
        int r = 0;
        #pragma unroll
        for (int j = 0; j < K_SEL; ++j) r += (sel[j] < my) ? 1 : 0;
        onecol[row * K_SEL + r] = my;
    }
}

// Dense-front writer. float4 unit u = s*(2048*256) + bid*256 + tid, s=0..31.
// Global out row r_global = u>>9 = s*1024 + (bid>>1); within-row float offset
// = (b&1)*1024 + tid*4. onecol flat index == r_global.
__global__ __launch_bounds__(256) void onehot_dense_front_kernel(
    const int* __restrict__ onecol,     // (32768)
    float* __restrict__ out)            // (32768, 2048) flat
{
    const int bid   = blockIdx.x;
    const int tid   = threadIdx.x;
    const int rbase = bid >> 1;
    const int cbase = ((bid & 1) << 10) + tid * 4;

    // preload this block's 32 one-hot columns (static-indexed -> registers)
    int pre[32];
    #pragma unroll
    for (int s = 0; s < 32; ++s) pre[s] = onecol[s * 1024 + rbase];

    // pure streaming store loop: device-wide dense ~8MB front per step s
    #pragma unroll
    for (int s = 0; s < 32; ++s) {
        const int one = pre[s];
        float4 a;
        a.x = (cbase + 0 == one) ? 1.0f : 0.0f;
        a.y = (cbase + 1 == one) ? 1.0f : 0.0f;
        a.z = (cbase + 2 == one) ? 1.0f : 0.0f;
        a.w = (cbase + 3 == one) ? 1.0f : 0.0f;
        float* dst = out + ((size_t)s * 2097152 + (size_t)bid * 1024 + tid * 4);
        *reinterpret_cast<float4*>(dst) = a;
    }
}

extern "C" void kernel_launch(void* const* d_in, const int* in_sizes, int n_in,
                              void* d_out, int out_size, void* d_ws, size_t ws_size,
                              hipStream_t stream) {
    const float* logits = (const float*)d_in[0];   // 64*2048
    const float* gn     = (const float*)d_in[1];   // 32*64*2048
    float* out          = (float*)d_out;           // 32*64*16*2048
    int*   onecol       = (int*)d_ws;              // 32768 ints (128KB scratch)

    hipLaunchKernelGGL(topk_select_kernel, dim3(NROWS), dim3(64), 0, stream,
                       logits, gn, onecol);
    hipLaunchKernelGGL(onehot_dense_front_kernel, dim3(2048), dim3(256), 0, stream,
                       onecol, out);
}

// Round 9
// 49.036 us; speedup vs baseline: 1.4840x; 1.4840x over previous
//
#include <hip/hip_runtime.h>
#include <math.h>

// out (32,64,16,2048) f32 = one_hot(ascending-sorted top-16 indices of logits+gn).
// Forward value of stop_gradient(hard-soft)+soft == hard exactly (0) / ~1ulp (1).
//
// Best-measured structure (R1): one wave per row, no LDS, no __syncthreads.
// Zero-stores for output row k interleaved with selection round k (store stream
// saturates from t=0, shuffle chains hide under it); one vmcnt(0) drain; then a
// single lane-parallel scattered store plants the 16 ones.
// Measured across 8 structures: write-dominated phases cap at ~5.0-5.5 TB/s on
// this chip (vendor fill at this size is slower); interleaving is the optimum.
#define K_SEL   16
#define VOCAB   2048
#define NROWS   2048   // BS(32) * D0(64)

__global__ __launch_bounds__(64) void topk_onehot_kernel(
    const float* __restrict__ logits,   // (64, 2048)
    const float* __restrict__ gn,       // (32, 64, 2048)
    float* __restrict__ out)            // (32, 64, 16, 2048)
{
    const int row  = blockIdx.x;        // row = bs*64 + d0
    const int d0   = row & 63;
    const int lane = threadIdx.x;       // 0..63 (one wave)

    const float* grow = gn     + (size_t)row * VOCAB;
    const float* lrow = logits + (size_t)d0  * VOCAB;
    float*       orow = out    + (size_t)row * (K_SEL * VOCAB);

    // lane owns columns c = seg*256 + lane*4 + j, seg=0..7, j=0..3
    float v[32];
    #pragma unroll
    for (int seg = 0; seg < 8; ++seg) {
        const int c = seg * 256 + lane * 4;
        const float4 g = *reinterpret_cast<const float4*>(grow + c);
        const float4 l = *reinterpret_cast<const float4*>(lrow + c);
        v[seg * 4 + 0] = l.x + g.x;
        v[seg * 4 + 1] = l.y + g.y;
        v[seg * 4 + 2] = l.z + g.z;
        v[seg * 4 + 3] = l.w + g.w;
    }

    // local argmax; ascending scan + strict '>' keeps lowest index on ties
    float lv = v[0]; int ls = 0;
    #pragma unroll
    for (int i = 1; i < 32; ++i) { if (v[i] > lv) { lv = v[i]; ls = i; } }

    const float4 z4 = make_float4(0.f, 0.f, 0.f, 0.f);
    int sel[K_SEL];

    #pragma unroll
    for (int k = 0; k < K_SEL; ++k) {
        // zero-store one output row per round (8 x float4, 1KB/instr coalesced)
        #pragma unroll
        for (int seg = 0; seg < 8; ++seg) {
            *reinterpret_cast<float4*>(orow + (size_t)k * VOCAB + seg * 256 + lane * 4) = z4;
        }
        // wave argmax via 64-lane butterfly on (value desc, col asc)
        float bv = lv;
        int   bc = ((ls >> 2) << 8) + lane * 4 + (ls & 3);
        #pragma unroll
        for (int off = 1; off < 64; off <<= 1) {
            const float ov = __shfl_xor(bv, off);
            const int   oc = __shfl_xor(bc, off);
            if (ov > bv || (ov == bv && oc < bc)) { bv = ov; bc = oc; }
        }
        sel[k] = bc;  // wave-uniform after butterfly
        // owner lane knocks out the winner and rescans its local max
        if (lane == ((bc >> 2) & 63)) {
            const int s = (((bc >> 8) & 7) << 2) | (bc & 3);
            lv = -INFINITY; ls = 0;
            #pragma unroll
            for (int i = 0; i < 32; ++i) {
                if (i == s) v[i] = -INFINITY;
                if (v[i] > lv) { lv = v[i]; ls = i; }
            }
        }
    }

    // drain zero stores (HW order + compiler reorder fence) before overwrites
    asm volatile("s_waitcnt vmcnt(0)" ::: "memory");

    // lanes 0..15 plant the 16 ones in ONE scattered store instruction:
    // lane k takes sel[k] (static cndmask chain), ranks it by ascending index
    // (distinct -> permutation), stores 1.0 at (rank, sel[k]).
    if (lane < K_SEL) {
        int my = sel[0];
        #pragma unroll
        for (int k = 1; k < K_SEL; ++k) { if (lane == k) my = sel[k]; }
        int r = 0;
        #pragma unroll
        for (int j = 0; j < K_SEL; ++j) r += (sel[j] < my) ? 1 : 0;
        orow[(size_t)r * VOCAB + my] = 1.0f;
    }
}

extern "C" void kernel_launch(void* const* d_in, const int* in_sizes, int n_in,
                              void* d_out, int out_size, void* d_ws, size_t ws_size,
                              hipStream_t stream) {
    const float* logits = (const float*)d_in[0];   // 64*2048
    const float* gn     = (const float*)d_in[1];   // 32*64*2048
    float* out          = (float*)d_out;           // 32*64*16*2048

    hipLaunchKernelGGL(topk_onehot_kernel, dim3(NROWS), dim3(64), 0, stream,
                       logits, gn, out);
}